// Round 7
// baseline (1149.229 us; speedup 1.0000x reference)
//
#include <hip/hip_runtime.h>
#include <math.h>

// Problem constants
#define NN 50000      // nodes
#define NE 800000     // edges
#define HD 512        // hidden
#define GN_EPS 1e-5f
#define NBCHUNK 196   // ceil(NN/256) for scan
#define GRIDM 391     // ceil(NN/128) GEMM grid rows
#define STATS_NB 512  // combine1 stats partial blocks

typedef __attribute__((ext_vector_type(4))) float f4;
typedef __attribute__((ext_vector_type(4))) float f32x4;
typedef __attribute__((ext_vector_type(8))) short short8;
typedef unsigned short u16;
typedef __attribute__((ext_vector_type(4))) unsigned short us4;
typedef __attribute__((ext_vector_type(8))) unsigned short us8;

typedef struct { int s; float w; } edge_t;   // packed (src, norm) 8B

static __device__ __forceinline__ float elu1(float v){ return v > 0.f ? v : expm1f(v); }

static __device__ __forceinline__ float bf2f(u16 u){
  union { unsigned int i; float f; } v; v.i = ((unsigned int)u) << 16; return v.f;
}
static __device__ __forceinline__ u16 f2bf(float f){
  union { float f; unsigned int i; } v; v.f = f;
  unsigned int b = v.i;
  b += 0x7FFFu + ((b >> 16) & 1u);   // round-to-nearest-even
  return (u16)(b >> 16);
}

// LDS read address for [row][128B] tiles: XOR the 16B-slot index with (row&7).
// Staging pre-swizzles the GLOBAL source so LDS dest stays linear (global_load_lds rule).
static __device__ __forceinline__ int lds_addr(int row, int chunkByte){
  return row*128 + (chunkByte ^ ((row & 7) << 4));
}

// async global(16B/lane) -> LDS (wave-uniform base + lane*16)
static __device__ __forceinline__ void gl16(const u16* g, u16* l) {
  __builtin_amdgcn_global_load_lds(
      (const __attribute__((address_space(1))) void*)g,
      (__attribute__((address_space(3))) void*)l, 16, 0, 0);
}

// ---------------- CSR build ----------------
__global__ void k_deg(const int* __restrict__ dst, const float* __restrict__ w,
                      float* __restrict__ deg, int* __restrict__ cnt) {
  int e = blockIdx.x*256 + threadIdx.x;
  if (e < NE) {
    int d = dst[e];
    atomicAdd(&deg[d], w[e]);
    atomicAdd(&cnt[d], 1);
  }
}

__global__ void k_dinv(float* __restrict__ deg) {
  int n = blockIdx.x*256 + threadIdx.x;
  if (n < NN) { float d = deg[n]; deg[n] = d > 0.f ? rsqrtf(d) : 0.f; }
}

// hierarchical scan: chunk-local inclusive -> chunk totals
__global__ void __launch_bounds__(256) k_scanA(const int* __restrict__ cnt,
                                               int* __restrict__ row_ptr,
                                               int* __restrict__ btot) {
  __shared__ int sh[256];
  int t = threadIdx.x, b = blockIdx.x;
  int i = b*256 + t;
  int v = (i < NN) ? cnt[i] : 0;
  sh[t] = v; __syncthreads();
  #pragma unroll
  for (int off = 1; off < 256; off <<= 1) {
    int x = (t >= off) ? sh[t-off] : 0;
    __syncthreads();
    sh[t] += x;
    __syncthreads();
  }
  if (i < NN) row_ptr[i+1] = sh[t];
  if (t == 255) btot[b] = sh[255];
}

__global__ void __launch_bounds__(256) k_scanB(const int* __restrict__ btot,
                                               int* __restrict__ boff) {
  __shared__ int sh[256];
  int t = threadIdx.x;
  int v = (t < NBCHUNK) ? btot[t] : 0;
  sh[t] = v; __syncthreads();
  #pragma unroll
  for (int off = 1; off < 256; off <<= 1) {
    int x = (t >= off) ? sh[t-off] : 0;
    __syncthreads();
    sh[t] += x;
    __syncthreads();
  }
  if (t < NBCHUNK) boff[t] = sh[t] - v;   // exclusive
}

__global__ void __launch_bounds__(256) k_scanC(int* __restrict__ row_ptr,
                                               const int* __restrict__ boff) {
  int t = threadIdx.x, b = blockIdx.x;
  int i = b*256 + t;
  if (i < NN) row_ptr[i+1] += boff[b];
  if (i == 0) row_ptr[0] = 0;
}

__global__ void k_fill(const int* __restrict__ src, const int* __restrict__ dst,
                       const float* __restrict__ w, const float* __restrict__ dinv,
                       const int* __restrict__ row_ptr, int* __restrict__ cursor,
                       edge_t* __restrict__ edges) {
  int e = blockIdx.x*256 + threadIdx.x;
  if (e < NE) {
    int s = src[e], d = dst[e];
    int pos = atomicAdd(&cursor[d], 1);
    int idx = row_ptr[d] + pos;
    edge_t ed; ed.s = s; ed.w = dinv[s] * w[e] * dinv[d];
    edges[idx] = ed;
  }
}

// ---------------- width-4 propagation (layers 1 & 3), all f32 ----------------
__global__ void k_prop4(const int* __restrict__ row_ptr, const edge_t* __restrict__ edges,
                        const f4* __restrict__ in1, const f4* __restrict__ in2,
                        const f4* __restrict__ base, const float* __restrict__ bias,
                        f4* __restrict__ out) {
  int n = blockIdx.x*256 + threadIdx.x;
  if (n >= NN) return;
  f4 acc = {0.f,0.f,0.f,0.f};
  int e0 = row_ptr[n], e1 = row_ptr[n+1];
  if (in2) {
    for (int e = e0; e < e1; ++e) {
      edge_t ed = edges[e];
      acc += ed.w * (in1[ed.s] + in2[ed.s]);
    }
  } else {
    for (int e = e0; e < e1; ++e) {
      edge_t ed = edges[e];
      acc += ed.w * in1[ed.s];
    }
  }
  if (base) acc += base[n];
  if (bias) { acc[0]+=bias[0]; acc[1]+=bias[1]; acc[2]+=bias[2]; acc[3]+=bias[3]; }
  out[n] = acc;
}

// ---------------- width-512 propagation on bf16, one wave per node ----------------
__global__ void __launch_bounds__(256) k_prop512_bf(
    const int* __restrict__ row_ptr, const edge_t* __restrict__ edges,
    const u16* __restrict__ in, u16* __restrict__ out) {
  int wv = threadIdx.x >> 6;
  int l  = threadIdx.x & 63;
  int n = blockIdx.x*4 + wv;
  if (n >= NN) return;
  int e0 = row_ptr[n], e1 = row_ptr[n+1];
  float acc[8] = {0.f,0.f,0.f,0.f,0.f,0.f,0.f,0.f};
  const u16* basep = in + l*8;
  for (int e = e0; e < e1; ++e) {
    edge_t ed = edges[e];
    us8 v = *reinterpret_cast<const us8*>(basep + (size_t)ed.s*HD);
    #pragma unroll
    for (int q = 0; q < 8; ++q) acc[q] += ed.w * bf2f(v[q]);
  }
  us8 o;
  #pragma unroll
  for (int q = 0; q < 8; ++q) o[q] = f2bf(acc[q]);
  *reinterpret_cast<us8*>(out + (size_t)n*HD + l*8) = o;
}

// ---------------- layer-1 combine fused with stats: bf16 out + column partials ----------------
__global__ void __launch_bounds__(256) k_combine1s(
    const f4* __restrict__ x, const f4* __restrict__ h1, const f4* __restrict__ h2,
    const f4* __restrict__ h3, const float* __restrict__ W1, const float* __restrict__ b1,
    u16* __restrict__ act, float* __restrict__ pS, float* __restrict__ pQ) {
  __shared__ float sdS[HD], sdQ[HD];
  int t = threadIdx.x;
  int half = t >> 7;
  int c4 = (t & 127) * 4;
  f4 wcol[16];
  #pragma unroll
  for (int kf = 0; kf < 16; ++kf)
    wcol[kf] = *reinterpret_cast<const f4*>(W1 + (size_t)kf*HD + c4);
  f4 bv = *reinterpret_cast<const f4*>(b1 + c4);
  f4 s = {0.f,0.f,0.f,0.f}, qq = {0.f,0.f,0.f,0.f};
  for (int n = blockIdx.x*2 + half; n < NN; n += gridDim.x*2) {
    f4 hv0 = x[n], hv1 = h1[n], hv2 = h2[n], hv3 = h3[n];
    f4 acc = bv;
    #pragma unroll
    for (int f = 0; f < 4; ++f) acc += hv0[f] * wcol[f];
    #pragma unroll
    for (int f = 0; f < 4; ++f) acc += hv1[f] * wcol[4+f];
    #pragma unroll
    for (int f = 0; f < 4; ++f) acc += hv2[f] * wcol[8+f];
    #pragma unroll
    for (int f = 0; f < 4; ++f) acc += hv3[f] * wcol[12+f];
    us4 o;
    #pragma unroll
    for (int e = 0; e < 4; ++e) {
      float v = elu1(acc[e]);
      s[e] += v; qq[e] += v*v;
      o[e] = f2bf(v);
    }
    *reinterpret_cast<us4*>(act + (size_t)n*HD + c4) = o;
  }
  if (half) {
    *reinterpret_cast<f4*>(&sdS[c4]) = s;
    *reinterpret_cast<f4*>(&sdQ[c4]) = qq;
  }
  __syncthreads();
  if (!half) {
    f4 ts = *reinterpret_cast<f4*>(&sdS[c4]) + s;
    f4 tq = *reinterpret_cast<f4*>(&sdQ[c4]) + qq;
    *reinterpret_cast<f4*>(&pS[(size_t)blockIdx.x*HD + c4]) = ts;
    *reinterpret_cast<f4*>(&pQ[(size_t)blockIdx.x*HD + c4]) = tq;
  }
}

// ---------------- reduce partials [nb][512] -> s1,s2 ----------------
__global__ void __launch_bounds__(256) k_reduce(
    const float* __restrict__ pS, const float* __restrict__ pQ, int nb,
    float* __restrict__ s1, float* __restrict__ s2) {
  int c = blockIdx.x*256 + threadIdx.x;
  if (c >= HD) return;
  float a = 0.f, b = 0.f;
  for (int i = 0; i < nb; ++i) {
    a += pS[(size_t)i*HD + c];
    b += pQ[(size_t)i*HD + c];
  }
  s1[c] = a; s2[c] = b;
}

// ---------------- GraphNorm scale/shift precompute: v_norm = sc*v + sh ----------------
__global__ void k_affine(const float* __restrict__ s1, const float* __restrict__ s2,
                         const float* __restrict__ gw, const float* __restrict__ gb,
                         const float* __restrict__ ga,
                         float* __restrict__ sc, float* __restrict__ sh) {
  int c = blockIdx.x*256 + threadIdx.x;
  if (c >= HD) return;
  float mu = s1[c]*(1.f/NN);
  float a  = ga[c];
  float var = s2[c]*(1.f/NN) - 2.f*a*mu*mu + a*a*mu*mu;
  float inv = rsqrtf(var + GN_EPS);
  sc[c] = gw[c]*inv;
  sh[c] = gb[c] - gw[c]*inv*a*mu;
}

// ---------------- in-place bf16 normalize with precomputed sc/sh ----------------
__global__ void k_norm_ip(u16* __restrict__ buf, const float* __restrict__ sc,
                          const float* __restrict__ sh) {
  size_t i = (size_t)blockIdx.x*256 + threadIdx.x;
  size_t total = (size_t)NN*HD/8;
  if (i >= total) return;
  int c = (int)((i*8) % HD);
  us8 v = reinterpret_cast<us8*>(buf)[i];
  #pragma unroll
  for (int e = 0; e < 8; ++e) v[e] = f2bf(bf2f(v[e])*sc[c+e] + sh[c+e]);
  reinterpret_cast<us8*>(buf)[i] = v;
}

// ---------------- W2 -> bf16 transposed: Bt[k][out][in] = bf16(W2[k][in][out]) ----------------
__global__ void k_w2t(const float* __restrict__ W2, u16* __restrict__ Bt) {
  size_t idx = (size_t)blockIdx.x*256 + threadIdx.x;
  if (idx >= (size_t)4*HD*HD) return;
  int i = (int)(idx & 511);          // in  (fastest -> coalesced write)
  int o = (int)((idx >> 9) & 511);   // out
  int k = (int)(idx >> 18);
  Bt[idx] = f2bf(W2[((size_t)k*HD + i)*HD + o]);
}

// ---------------- MFMA bf16 dual-source GEMM (K=1024): Cbf (+)= A0@B0^T + A1@B1^T ----------------
// m97 structure: global_load_lds width-16 staging, single LDS buffer, 2 barriers/K-step.
// Swizzle via pre-swizzled GLOBAL source (linear LDS dest) + swizzled ds_read (rule #21).
// FINAL=0: Cbf = bf16(partial).  FINAL=1: v=elu(bf2f(Cbf)+acc+bias); Cbf=v; per-channel stats.
#define BM 128
#define BN 128
#define BKS 64
template<int FINAL>
__global__ void __launch_bounds__(256) k_gemm2(
    const u16* __restrict__ A0, const u16* __restrict__ A1,
    const u16* __restrict__ B0, const u16* __restrict__ B1,
    u16* __restrict__ Cbf, const float* __restrict__ bias,
    float* __restrict__ pS, float* __restrict__ pQ, int M) {
  __shared__ u16 As[BM*BKS];   // 16 KB, rows of 128B, linear layout (content pre-swizzled)
  __shared__ u16 Bs[BN*BKS];   // 16 KB
  __shared__ float sdS[BN], sdQ[BN];
  int t = threadIdx.x;

  // XCD-bijective remap (m204), col-fastest within consecutive ids
  int nwg = gridDim.x;            // GRIDM*4
  int q = nwg >> 3, r = nwg & 7;
  int xcd = blockIdx.x & 7, sub = blockIdx.x >> 3;
  int nid = (xcd < r ? xcd*(q+1) : r*(q+1) + (xcd - r)*q) + sub;
  int bmi = nid >> 2;             // row-panel index (0..GRIDM-1)
  int bni = nid & 3;              // col-panel index (0..3)
  int bm = bmi * BM, bn = bni * BN;

  int w  = t >> 6;
  int l  = t & 63;
  int wr = (w >> 1) * 64;
  int wc = (w & 1) * 64;
  int lr = l & 15;
  int lq = l >> 4;

  if (FINAL && t < BN) { sdS[t] = 0.f; sdQ[t] = 0.f; }

  // staging map: 4 slots/thread; slot s -> row = s>>3, slot-in-row c8 = s&7.
  // LDS dest is LINEAR (byte s*16, wave-contiguous); global source chunk is
  // pre-swizzled: chunk = c8 ^ (row&7), so lds[row][c8] = global[row][c8^(row&7)].
  size_t aoffs[4], boffs[4];
  int ldst[4];
  #pragma unroll
  for (int p2 = 0; p2 < 4; ++p2) {
    int s = p2*256 + t;
    int row = s >> 3, c8 = s & 7;
    int chunk = c8 ^ (row & 7);
    int ga = bm + row; if (ga >= M) ga = M - 1;
    aoffs[p2] = (size_t)ga*HD + chunk*8;
    boffs[p2] = (size_t)(bn + row)*HD + chunk*8;
    ldst[p2] = s*16;
  }

  f32x4 acc[4][4];
  #pragma unroll
  for (int i = 0; i < 4; ++i)
    #pragma unroll
    for (int j = 0; j < 4; ++j) acc[i][j] = (f32x4){0.f,0.f,0.f,0.f};

  for (int h = 0; h < 16; ++h) {
    const u16* Ab = (h < 8) ? A0 : A1;
    const u16* Bb = (h < 8) ? B0 : B1;
    int kb = (h & 7) * BKS;
    __syncthreads();   // previous tile's ds_reads complete (lgkm drained at barrier)
    #pragma unroll
    for (int p2 = 0; p2 < 4; ++p2) {
      gl16(Ab + aoffs[p2] + kb, (u16*)((char*)As + ldst[p2]));
      gl16(Bb + boffs[p2] + kb, (u16*)((char*)Bs + ldst[p2]));
    }
    __syncthreads();   // vmcnt(0) drain at barrier -> tile resident
    #pragma unroll
    for (int ks = 0; ks < 2; ++ks) {
      short8 af[4], bfr[4];
      #pragma unroll
      for (int mi = 0; mi < 4; ++mi)
        af[mi] = *reinterpret_cast<const short8*>(
            (char*)As + lds_addr(wr + mi*16 + lr, ks*64 + lq*16));
      #pragma unroll
      for (int ni = 0; ni < 4; ++ni)
        bfr[ni] = *reinterpret_cast<const short8*>(
            (char*)Bs + lds_addr(wc + ni*16 + lr, ks*64 + lq*16));
      #pragma unroll
      for (int mi = 0; mi < 4; ++mi)
        #pragma unroll
        for (int ni = 0; ni < 4; ++ni)
          acc[mi][ni] = __builtin_amdgcn_mfma_f32_16x16x32_bf16(af[mi], bfr[ni], acc[mi][ni], 0, 0, 0);
    }
  }

  if (!FINAL) {
    #pragma unroll
    for (int mi = 0; mi < 4; ++mi)
      #pragma unroll
      for (int ni = 0; ni < 4; ++ni)
        #pragma unroll
        for (int rr = 0; rr < 4; ++rr) {
          int gm = bm + wr + mi*16 + lq*4 + rr;
          int gn = bn + wc + ni*16 + lr;
          if (gm < M) Cbf[(size_t)gm*HD + gn] = f2bf(acc[mi][ni][rr]);
        }
  } else {
    float psum[4] = {0.f,0.f,0.f,0.f}, qsum[4] = {0.f,0.f,0.f,0.f};
    #pragma unroll
    for (int ni = 0; ni < 4; ++ni) {
      int gn = bn + wc + ni*16 + lr;
      float bgn = bias[gn];
      #pragma unroll
      for (int mi = 0; mi < 4; ++mi)
        #pragma unroll
        for (int rr = 0; rr < 4; ++rr) {
          int gm = bm + wr + mi*16 + lq*4 + rr;
          if (gm < M) {
            u16* cp = &Cbf[(size_t)gm*HD + gn];
            float v = elu1(bf2f(*cp) + acc[mi][ni][rr] + bgn);
            *cp = f2bf(v);
            psum[ni] += v; qsum[ni] += v*v;
          }
        }
    }
    #pragma unroll
    for (int ni = 0; ni < 4; ++ni) {
      psum[ni] += __shfl_xor(psum[ni], 16, 64);
      psum[ni] += __shfl_xor(psum[ni], 32, 64);
      qsum[ni] += __shfl_xor(qsum[ni], 16, 64);
      qsum[ni] += __shfl_xor(qsum[ni], 32, 64);
    }
    if (lq == 0) {
      #pragma unroll
      for (int ni = 0; ni < 4; ++ni) {
        atomicAdd(&sdS[wc + ni*16 + lr], psum[ni]);   // exactly 2 contribs/slot
        atomicAdd(&sdQ[wc + ni*16 + lr], qsum[ni]);
      }
    }
    __syncthreads();
    if (t < BN) {
      pS[(size_t)bmi*HD + bn + t] = sdS[t];
      pQ[(size_t)bmi*HD + bn + t] = sdQ[t];
    }
  }
}

// ---------------- layer-3 linears (bf16 act) with fused GraphNorm affine ----------------
__global__ void __launch_bounds__(256) k_lin3(
    const u16* __restrict__ act, const float* __restrict__ sc, const float* __restrict__ sh,
    const float* __restrict__ W3,
    f4* __restrict__ p0, f4* __restrict__ p1, f4* __restrict__ p2, f4* __restrict__ p3) {
  int wave = threadIdx.x / 64;
  int lane = threadIdx.x % 64;
  int n = blockIdx.x*4 + wave;
  if (n >= NN) return;
  float part[4][4] = {};
  #pragma unroll
  for (int jj = 0; jj < 8; ++jj) {
    int j = lane + jj*64;
    float v = sc[j]*bf2f(act[(size_t)n*HD + j]) + sh[j];
    #pragma unroll
    for (int k = 0; k < 4; ++k) {
      f4 wv = *reinterpret_cast<const f4*>(W3 + ((size_t)k*HD + j)*4);
      #pragma unroll
      for (int c = 0; c < 4; ++c) part[k][c] += v * wv[c];
    }
  }
  #pragma unroll
  for (int k = 0; k < 4; ++k)
    #pragma unroll
    for (int c = 0; c < 4; ++c) {
      float s = part[k][c];
      #pragma unroll
      for (int off = 32; off >= 1; off >>= 1) s += __shfl_xor(s, off, 64);
      part[k][c] = s;
    }
  if (lane == 0) {
    f4 v0 = {part[0][0],part[0][1],part[0][2],part[0][3]};
    f4 v1 = {part[1][0],part[1][1],part[1][2],part[1][3]};
    f4 v2 = {part[2][0],part[2][1],part[2][2],part[2][3]};
    f4 v3 = {part[3][0],part[3][1],part[3][2],part[3][3]};
    p0[n]=v0; p1[n]=v1; p2[n]=v2; p3[n]=v3;
  }
}

// ---------------- host launch ----------------
extern "C" void kernel_launch(void* const* d_in, const int* in_sizes, int n_in,
                              void* d_out, int out_size, void* d_ws, size_t ws_size,
                              hipStream_t stream) {
  const float* x   = (const float*)d_in[0];
  const int*   ei  = (const int*)d_in[1];
  const int*   src = ei;
  const int*   dst = ei + NE;
  const float* w   = (const float*)d_in[2];
  const float* W1  = (const float*)d_in[3];
  const float* b1  = (const float*)d_in[4];
  const float* W2  = (const float*)d_in[5];
  const float* b2  = (const float*)d_in[6];
  const float* W3  = (const float*)d_in[7];
  const float* b3  = (const float*)d_in[8];
  const float* g1w = (const float*)d_in[9];
  const float* g1b = (const float*)d_in[10];
  const float* g1a = (const float*)d_in[11];
  const float* g2w = (const float*)d_in[12];
  const float* g2b = (const float*)d_in[13];
  const float* g2a = (const float*)d_in[14];

  char* p = (char*)d_ws;
  auto alloc = [&](size_t bytes) -> void* {
    void* r = (void*)p;
    p += (bytes + 255) & ~(size_t)255;
    return r;
  };
  float* deg      = (float*)alloc(NN*4);
  int*   cnt      = (int*)  alloc(NN*4);
  int*   row_ptr  = (int*)  alloc((NN+1)*4);
  int*   cursor   = (int*)  alloc(NN*4);
  int*   btot     = (int*)  alloc(256*4);
  int*   boff     = (int*)  alloc(256*4);
  edge_t* edges   = (edge_t*)alloc((size_t)NE*8);
  f4*    h1       = (f4*)   alloc((size_t)NN*16);
  f4*    h2       = (f4*)   alloc((size_t)NN*16);
  f4*    h3       = (f4*)   alloc((size_t)NN*16);
  f4*    p0       = (f4*)   alloc((size_t)NN*16);
  f4*    p1       = (f4*)   alloc((size_t)NN*16);
  f4*    p2       = (f4*)   alloc((size_t)NN*16);
  f4*    p3       = (f4*)   alloc((size_t)NN*16);
  f4*    t1       = (f4*)   alloc((size_t)NN*16);
  f4*    t2       = (f4*)   alloc((size_t)NN*16);
  float* stats    = (float*)alloc(1024*4);
  float* s1 = stats, *s2 = stats + 512;
  float* scb      = (float*)alloc(HD*4);
  float* shb      = (float*)alloc(HD*4);
  float* pS       = (float*)alloc((size_t)STATS_NB*HD*4);   // 1 MB
  float* pQ       = (float*)alloc((size_t)STATS_NB*HD*4);   // 1 MB
  u16*   W2T      = (u16*)  alloc((size_t)4*HD*HD*2);       // 2 MB
  // big buffers: 3 x 51.2 MB bf16  (~175 MB total)
  u16*   bfA      = (u16*)  alloc((size_t)NN*HD*2);
  u16*   bfB      = (u16*)  alloc((size_t)NN*HD*2);
  u16*   bfC      = (u16*)  alloc((size_t)NN*HD*2);   // C partial then act2

  const int TPB = 256;
  int gridE = (NE + TPB - 1)/TPB;
  int gridN = (NN + TPB - 1)/TPB;
  int gridIp = (int)(((size_t)NN*HD/8 + 255)/256);
  int gridP = (NN + 3)/4;

  // CSR + norm
  hipMemsetAsync(deg, 0, NN*4, stream);
  hipMemsetAsync(cnt, 0, NN*4, stream);
  k_deg<<<gridE, TPB, 0, stream>>>(dst, w, deg, cnt);
  k_dinv<<<gridN, TPB, 0, stream>>>(deg);
  k_scanA<<<NBCHUNK, 256, 0, stream>>>(cnt, row_ptr, btot);
  k_scanB<<<1, 256, 0, stream>>>(btot, boff);
  k_scanC<<<NBCHUNK, 256, 0, stream>>>(row_ptr, boff);
  hipMemsetAsync(cursor, 0, NN*4, stream);
  k_fill<<<gridE, TPB, 0, stream>>>(src, dst, w, deg, row_ptr, cursor, edges);
  k_w2t<<<(4*HD*HD + 255)/256, 256, 0, stream>>>(W2, W2T);

  // Layer 1: hops, then fused combine+ELU+stats -> bf16 act (pre-norm) in bfA
  k_prop4<<<gridN, TPB, 0, stream>>>(row_ptr, edges, (const f4*)x, nullptr, nullptr, nullptr, h1);
  k_prop4<<<gridN, TPB, 0, stream>>>(row_ptr, edges, h1, nullptr, nullptr, nullptr, h2);
  k_prop4<<<gridN, TPB, 0, stream>>>(row_ptr, edges, h2, nullptr, nullptr, nullptr, h3);
  k_combine1s<<<STATS_NB, 256, 0, stream>>>((const f4*)x, h1, h2, h3, W1, b1, bfA, pS, pQ);
  k_reduce<<<2, 256, 0, stream>>>(pS, pQ, STATS_NB, s1, s2);
  k_affine<<<2, 256, 0, stream>>>(s1, s2, g1w, g1b, g1a, scb, shb);
  k_norm_ip<<<gridIp, 256, 0, stream>>>(bfA, scb, shb);

  // Layer 2: h0=bfA, h1=prop(h0)=bfB -> GEMM1 writes Cbf (bf16 partial);
  //          h2=prop(h1)=bfA, h3=prop(h2)=bfB -> GEMM2 accumulates + bias+ELU+stats in-place
  k_prop512_bf<<<gridP, 256, 0, stream>>>(row_ptr, edges, bfA, bfB);
  k_gemm2<0><<<GRIDM*4, 256, 0, stream>>>(bfA, bfB, W2T, W2T + (size_t)HD*HD,
                                          bfC, nullptr, nullptr, nullptr, NN);
  k_prop512_bf<<<gridP, 256, 0, stream>>>(row_ptr, edges, bfB, bfA);
  k_prop512_bf<<<gridP, 256, 0, stream>>>(row_ptr, edges, bfA, bfB);
  k_gemm2<1><<<GRIDM*4, 256, 0, stream>>>(bfA, bfB, W2T + 2*(size_t)HD*HD, W2T + 3*(size_t)HD*HD,
                                          bfC, b2, pS, pQ, NN);

  // GraphNorm 2 affine from GEMM-fused partials
  k_reduce<<<2, 256, 0, stream>>>(pS, pQ, GRIDM, s1, s2);
  k_affine<<<2, 256, 0, stream>>>(s1, s2, g2w, g2b, g2a, scb, shb);

  // Layer 3: fused-norm narrow linears, then Horner with width-4 propagations
  k_lin3<<<gridP, 256, 0, stream>>>(bfC, scb, shb, W3, p0, p1, p2, p3);
  k_prop4<<<gridN, TPB, 0, stream>>>(row_ptr, edges, p3, nullptr, nullptr, nullptr, t1);
  k_prop4<<<gridN, TPB, 0, stream>>>(row_ptr, edges, p2, t1, nullptr, nullptr, t2);
  k_prop4<<<gridN, TPB, 0, stream>>>(row_ptr, edges, p1, t2, p0, b3, (f4*)d_out);
}